// Round 1
// baseline (649.817 us; speedup 1.0000x reference)
//
#include <hip/hip_runtime.h>
#include <math.h>

#define NB 64
#define IMG_HW 784
#define IMG_W 28
#define BN_EPS 1e-5f

// ---------------------------------------------------------------------------
// absmax over a weight tensor -> uint-encoded float slot (bitwise atomicMax
// works because |w| >= 0 and IEEE non-negative floats order as uints)
// ---------------------------------------------------------------------------
__global__ void absmax_kernel(const float* __restrict__ w, int n,
                              unsigned int* __restrict__ slot) {
    float m = 0.f;
    for (int i = blockIdx.x * blockDim.x + threadIdx.x; i < n;
         i += gridDim.x * blockDim.x)
        m = fmaxf(m, fabsf(w[i]));
#pragma unroll
    for (int off = 32; off > 0; off >>= 1)
        m = fmaxf(m, __shfl_down(m, off, 64));
    __shared__ float sm[16];
    int lane = threadIdx.x & 63, wid = threadIdx.x >> 6;
    if (lane == 0) sm[wid] = m;
    __syncthreads();
    if (threadIdx.x == 0) {
        int nw = blockDim.x >> 6;
        float b = sm[0];
        for (int i = 1; i < nw; ++i) b = fmaxf(b, sm[i]);
        atomicMax(slot, __float_as_uint(b));
    }
}

// ---------------------------------------------------------------------------
// 1x1 conv = per-image GEMM: Y[n,co,hw] = sum_ci Wq[co,ci] * X[n,ci,hw] + b[co]
// 64x64 tile, 256 threads, 4x4 register blocking, fp32.
// A_s stored transposed [k][co] so both fragment reads are float4.
// ---------------------------------------------------------------------------
__global__ __launch_bounds__(256) void conv1x1_kernel(
    const float* __restrict__ X, const float* __restrict__ Wt,
    const float* __restrict__ bias, const unsigned int* __restrict__ amax,
    float* __restrict__ Y, int M, int K)
{
    __shared__ float A_s[16][64];
    __shared__ float B_s[16][64];
    const int n   = blockIdx.z;
    const int co0 = blockIdx.y * 64;
    const int hw0 = blockIdx.x * 64;
    const int tid = threadIdx.x;
    const int tx  = tid & 15, ty = tid >> 4;

    const float absmax    = __uint_as_float(*amax);
    const float scale     = absmax * (1.0f / 127.0f);
    const float inv_scale = 127.0f / absmax;

    const float* __restrict__ Xn = X + (size_t)n * K * IMG_HW;

    float acc[4][4] = {};

    const int lco  = tid >> 2;          // A: local output row this thread loads
    const int akk  = (tid & 3) * 4;     // A: k offset (float4)
    const int bkk  = (tid * 4) >> 6;    // B: k row
    const int bcol = (tid * 4) & 63;    // B: col (float4)
    const bool bvalid = (hw0 + bcol) < IMG_HW;

    for (int k0 = 0; k0 < K; k0 += 16) {
        float4 wv = *reinterpret_cast<const float4*>(
            &Wt[(size_t)(co0 + lco) * K + k0 + akk]);
        A_s[akk + 0][lco] = rintf(wv.x * inv_scale) * scale;
        A_s[akk + 1][lco] = rintf(wv.y * inv_scale) * scale;
        A_s[akk + 2][lco] = rintf(wv.z * inv_scale) * scale;
        A_s[akk + 3][lco] = rintf(wv.w * inv_scale) * scale;

        float4 xv = make_float4(0.f, 0.f, 0.f, 0.f);
        if (bvalid)
            xv = *reinterpret_cast<const float4*>(
                &Xn[(size_t)(k0 + bkk) * IMG_HW + hw0 + bcol]);
        *reinterpret_cast<float4*>(&B_s[bkk][bcol]) = xv;

        __syncthreads();
#pragma unroll
        for (int k = 0; k < 16; ++k) {
            float4 a = *reinterpret_cast<const float4*>(&A_s[k][ty * 4]);
            float4 b = *reinterpret_cast<const float4*>(&B_s[k][tx * 4]);
            float av[4] = {a.x, a.y, a.z, a.w};
            float bv[4] = {b.x, b.y, b.z, b.w};
#pragma unroll
            for (int i = 0; i < 4; ++i)
#pragma unroll
                for (int j = 0; j < 4; ++j)
                    acc[i][j] += av[i] * bv[j];
        }
        __syncthreads();
    }

    const int hwbase = hw0 + tx * 4;
    if (hwbase < IMG_HW) {
#pragma unroll
        for (int i = 0; i < 4; ++i) {
            int co = co0 + ty * 4 + i;
            float bb = bias[co];
            float4 o = make_float4(acc[i][0] + bb, acc[i][1] + bb,
                                   acc[i][2] + bb, acc[i][3] + bb);
            *reinterpret_cast<float4*>(
                &Y[((size_t)n * M + co) * IMG_HW + hwbase]) = o;
        }
    }
}

// ---------------------------------------------------------------------------
// 3x3 conv pad=1 as implicit GEMM: K = 128*9 = 1152, im2col done in the
// B-tile LDS load. Same 64x64 / 4x4 structure as conv1x1.
// ---------------------------------------------------------------------------
__global__ __launch_bounds__(256) void conv3x3_kernel(
    const float* __restrict__ X, const float* __restrict__ Wt,
    const float* __restrict__ bias, const unsigned int* __restrict__ amax,
    float* __restrict__ Y)
{
    const int M = 128, K = 1152, Cin = 128;
    __shared__ float A_s[16][64];
    __shared__ float B_s[16][64];
    const int n   = blockIdx.z;
    const int co0 = blockIdx.y * 64;
    const int hw0 = blockIdx.x * 64;
    const int tid = threadIdx.x;
    const int tx  = tid & 15, ty = tid >> 4;

    const float absmax    = __uint_as_float(*amax);
    const float scale     = absmax * (1.0f / 127.0f);
    const float inv_scale = 127.0f / absmax;

    float acc[4][4] = {};

    const int lco  = tid >> 2;
    const int akk  = (tid & 3) * 4;
    const int bkk  = (tid * 4) >> 6;
    const int bcol = (tid * 4) & 63;

    for (int k0 = 0; k0 < K; k0 += 16) {
        float4 wv = *reinterpret_cast<const float4*>(
            &Wt[(size_t)(co0 + lco) * K + k0 + akk]);
        A_s[akk + 0][lco] = rintf(wv.x * inv_scale) * scale;
        A_s[akk + 1][lco] = rintf(wv.y * inv_scale) * scale;
        A_s[akk + 2][lco] = rintf(wv.z * inv_scale) * scale;
        A_s[akk + 3][lco] = rintf(wv.w * inv_scale) * scale;

        // implicit im2col B load (scalar, bounds-checked)
        {
            int k  = k0 + bkk;
            int ci = k / 9;
            int r  = k - ci * 9;
            int kh = r / 3;
            int kw = r - kh * 3;
            const float* __restrict__ Xc =
                X + ((size_t)n * Cin + ci) * IMG_HW;
#pragma unroll
            for (int e = 0; e < 4; ++e) {
                int hw = hw0 + bcol + e;
                float v = 0.f;
                if (hw < IMG_HW) {
                    int h  = hw / IMG_W;
                    int w  = hw - h * IMG_W;
                    int hp = h + kh - 1;
                    int wp = w + kw - 1;
                    if (hp >= 0 && hp < IMG_W && wp >= 0 && wp < IMG_W)
                        v = Xc[hp * IMG_W + wp];
                }
                B_s[bkk][bcol + e] = v;
            }
        }

        __syncthreads();
#pragma unroll
        for (int k = 0; k < 16; ++k) {
            float4 a = *reinterpret_cast<const float4*>(&A_s[k][ty * 4]);
            float4 b = *reinterpret_cast<const float4*>(&B_s[k][tx * 4]);
            float av[4] = {a.x, a.y, a.z, a.w};
            float bv[4] = {b.x, b.y, b.z, b.w};
#pragma unroll
            for (int i = 0; i < 4; ++i)
#pragma unroll
                for (int j = 0; j < 4; ++j)
                    acc[i][j] += av[i] * bv[j];
        }
        __syncthreads();
    }

    const int hwbase = hw0 + tx * 4;
    if (hwbase < IMG_HW) {
#pragma unroll
        for (int i = 0; i < 4; ++i) {
            int co = co0 + ty * 4 + i;
            float bb = bias[co];
            float4 o = make_float4(acc[i][0] + bb, acc[i][1] + bb,
                                   acc[i][2] + bb, acc[i][3] + bb);
            *reinterpret_cast<float4*>(
                &Y[((size_t)n * M + co) * IMG_HW + hwbase]) = o;
        }
    }
}

// ---------------------------------------------------------------------------
// per-channel batch stats over (N,H,W): one block per channel, double
// accumulation -> bitwise deterministic (no float atomics).
// ---------------------------------------------------------------------------
__global__ __launch_bounds__(1024) void stats_kernel(
    const float* __restrict__ Y, int C,
    float* __restrict__ mean, float* __restrict__ var)
{
    const int c = blockIdx.x;
    const int total = NB * IMG_HW;
    double s = 0.0, s2 = 0.0;
    for (int i = threadIdx.x; i < total; i += blockDim.x) {
        int n  = i / IMG_HW;
        int hw = i - n * IMG_HW;
        float v = Y[((size_t)n * C + c) * IMG_HW + hw];
        s  += v;
        s2 += (double)v * v;
    }
#pragma unroll
    for (int off = 32; off > 0; off >>= 1) {
        s  += __shfl_down(s, off, 64);
        s2 += __shfl_down(s2, off, 64);
    }
    __shared__ double sd[16], sd2[16];
    int lane = threadIdx.x & 63, wid = threadIdx.x >> 6;
    if (lane == 0) { sd[wid] = s; sd2[wid] = s2; }
    __syncthreads();
    if (threadIdx.x == 0) {
        int nw = blockDim.x >> 6;
        double ts = 0.0, ts2 = 0.0;
        for (int i = 0; i < nw; ++i) { ts += sd[i]; ts2 += sd2[i]; }
        double m = ts / total;
        mean[c] = (float)m;
        var[c]  = (float)(ts2 / total - m * m);
    }
}

// ---------------------------------------------------------------------------
// in-place BN + ReLU (float4)
// ---------------------------------------------------------------------------
__global__ void bn_relu_kernel(float* __restrict__ Y,
    const float* __restrict__ mean, const float* __restrict__ var,
    const float* __restrict__ gamma, const float* __restrict__ beta,
    int C, int total4)
{
    int stride = gridDim.x * blockDim.x;
    for (int i = blockIdx.x * blockDim.x + threadIdx.x; i < total4; i += stride) {
        int c = (i / (IMG_HW / 4)) % C;
        float m  = mean[c];
        float rs = rsqrtf(var[c] + BN_EPS) * gamma[c];
        float b  = beta[c];
        float4 v = reinterpret_cast<float4*>(Y)[i];
        v.x = fmaxf(fmaf(v.x - m, rs, b), 0.f);
        v.y = fmaxf(fmaf(v.y - m, rs, b), 0.f);
        v.z = fmaxf(fmaf(v.z - m, rs, b), 0.f);
        v.w = fmaxf(fmaf(v.w - m, rs, b), 0.f);
        reinterpret_cast<float4*>(Y)[i] = v;
    }
}

// ---------------------------------------------------------------------------
// final: out = relu(BN3(out) + x), in-place on d_out (float4)
// ---------------------------------------------------------------------------
__global__ void bn_add_relu_kernel(float* __restrict__ Y,
    const float* __restrict__ X,
    const float* __restrict__ mean, const float* __restrict__ var,
    const float* __restrict__ gamma, const float* __restrict__ beta,
    int C, int total4)
{
    int stride = gridDim.x * blockDim.x;
    for (int i = blockIdx.x * blockDim.x + threadIdx.x; i < total4; i += stride) {
        int c = (i / (IMG_HW / 4)) % C;
        float m  = mean[c];
        float rs = rsqrtf(var[c] + BN_EPS) * gamma[c];
        float b  = beta[c];
        float4 v  = reinterpret_cast<float4*>(Y)[i];
        float4 xv = reinterpret_cast<const float4*>(X)[i];
        v.x = fmaxf(fmaf(v.x - m, rs, b) + xv.x, 0.f);
        v.y = fmaxf(fmaf(v.y - m, rs, b) + xv.y, 0.f);
        v.z = fmaxf(fmaf(v.z - m, rs, b) + xv.z, 0.f);
        v.w = fmaxf(fmaf(v.w - m, rs, b) + xv.w, 0.f);
        reinterpret_cast<float4*>(Y)[i] = v;
    }
}

// ---------------------------------------------------------------------------
extern "C" void kernel_launch(void* const* d_in, const int* in_sizes, int n_in,
                              void* d_out, int out_size, void* d_ws, size_t ws_size,
                              hipStream_t stream)
{
    const float* x   = (const float*)d_in[0];
    const float* w1  = (const float*)d_in[1];
    const float* b1  = (const float*)d_in[2];
    const float* g1  = (const float*)d_in[3];
    const float* be1 = (const float*)d_in[4];
    const float* w2  = (const float*)d_in[5];
    const float* b2  = (const float*)d_in[6];
    const float* g2  = (const float*)d_in[7];
    const float* be2 = (const float*)d_in[8];
    const float* w3  = (const float*)d_in[9];
    const float* b3  = (const float*)d_in[10];
    const float* g3  = (const float*)d_in[11];
    const float* be3 = (const float*)d_in[12];
    float* out = (float*)d_out;
    float* ws  = (float*)d_ws;

    unsigned int* amax = (unsigned int*)ws;          // 3 slots
    float* mean1 = ws + 16;    float* var1 = ws + 144;
    float* mean2 = ws + 272;   float* var2 = ws + 400;
    float* mean3 = ws + 528;   float* var3 = ws + 1040;
    float* y1 = ws + 2048;                           // 64*128*784 floats
    float* y2 = y1 + (size_t)NB * 128 * IMG_HW;      // 64*128*784 floats

    hipMemsetAsync(amax, 0, 3 * sizeof(unsigned int), stream);

    absmax_kernel<<<64, 256, 0, stream>>>(w1, 128 * 512, amax + 0);
    absmax_kernel<<<64, 256, 0, stream>>>(w2, 128 * 128 * 9, amax + 1);
    absmax_kernel<<<64, 256, 0, stream>>>(w3, 512 * 128, amax + 2);

    // conv1: M=128, K=512
    conv1x1_kernel<<<dim3(13, 2, NB), 256, 0, stream>>>(x, w1, b1, amax + 0,
                                                        y1, 128, 512);
    stats_kernel<<<128, 1024, 0, stream>>>(y1, 128, mean1, var1);
    bn_relu_kernel<<<2048, 256, 0, stream>>>(y1, mean1, var1, g1, be1, 128,
                                             NB * 128 * (IMG_HW / 4));

    // conv2: 3x3 implicit GEMM, M=128, K=1152
    conv3x3_kernel<<<dim3(13, 2, NB), 256, 0, stream>>>(y1, w2, b2, amax + 1, y2);
    stats_kernel<<<128, 1024, 0, stream>>>(y2, 128, mean2, var2);
    bn_relu_kernel<<<2048, 256, 0, stream>>>(y2, mean2, var2, g2, be2, 128,
                                             NB * 128 * (IMG_HW / 4));

    // conv3: M=512, K=128 -> writes y3 directly into d_out
    conv1x1_kernel<<<dim3(13, 8, NB), 256, 0, stream>>>(y2, w3, b3, amax + 2,
                                                        out, 512, 128);
    stats_kernel<<<512, 1024, 0, stream>>>(out, 512, mean3, var3);
    bn_add_relu_kernel<<<2048, 256, 0, stream>>>(out, x, mean3, var3, g3, be3,
                                                 512, NB * 512 * (IMG_HW / 4));
}

// Round 2
// 268.489 us; speedup vs baseline: 2.4203x; 2.4203x over previous
//
#include <hip/hip_runtime.h>
#include <hip/hip_bf16.h>
#include <math.h>

#define NB 64
#define IMG_HW 784
#define IMG_W 28
#define BN_EPS 1e-5f

typedef __attribute__((ext_vector_type(8))) short bf16x8;
typedef __attribute__((ext_vector_type(4))) float f32x4;

static __device__ __forceinline__ ushort f2bf(float f) {
    __hip_bfloat16 h = __float2bfloat16(f);
    return *reinterpret_cast<ushort*>(&h);
}
static __device__ __forceinline__ float bf2f(ushort u) {
    return __uint_as_float(((unsigned int)u) << 16);
}

// ---------------------------------------------------------------------------
// absmax -> uint-encoded float (bitwise atomicMax valid for non-negative)
// ---------------------------------------------------------------------------
__global__ void absmax_kernel(const float* __restrict__ w, int n,
                              unsigned int* __restrict__ slot) {
    float m = 0.f;
    for (int i = blockIdx.x * blockDim.x + threadIdx.x; i < n;
         i += gridDim.x * blockDim.x)
        m = fmaxf(m, fabsf(w[i]));
#pragma unroll
    for (int off = 32; off > 0; off >>= 1)
        m = fmaxf(m, __shfl_down(m, off, 64));
    __shared__ float sm[4];
    int lane = threadIdx.x & 63, wid = threadIdx.x >> 6;
    if (lane == 0) sm[wid] = m;
    __syncthreads();
    if (threadIdx.x == 0) {
        float b = fmaxf(fmaxf(sm[0], sm[1]), fmaxf(sm[2], sm[3]));
        atomicMax(slot, __float_as_uint(b));
    }
}

// ---------------------------------------------------------------------------
// quantize fp32 weights -> bf16 (same layout)
// ---------------------------------------------------------------------------
__global__ void prequant_kernel(const float* __restrict__ w, int n,
                                const unsigned int* __restrict__ amax,
                                ushort* __restrict__ out) {
    float am = __uint_as_float(*amax);
    float scale = am * (1.0f / 127.0f);
    float inv   = 127.0f / am;
    for (int i = blockIdx.x * blockDim.x + threadIdx.x; i < n;
         i += gridDim.x * blockDim.x)
        out[i] = f2bf(rintf(w[i] * inv) * scale);
}

// w2 [co][ci][r=kh*3+kw] -> quantized bf16 [co][r*128+ci]
__global__ void prequant_w2_kernel(const float* __restrict__ w,
                                   const unsigned int* __restrict__ amax,
                                   ushort* __restrict__ out) {
    float am = __uint_as_float(*amax);
    float scale = am * (1.0f / 127.0f);
    float inv   = 127.0f / am;
    int i = blockIdx.x * blockDim.x + threadIdx.x;   // 147456 total
    if (i >= 128 * 128 * 9) return;
    int co  = i / 1152;
    int rem = i - co * 1152;
    int ci  = rem / 9;
    int r   = rem - ci * 9;
    out[co * 1152 + r * 128 + ci] = f2bf(rintf(w[i] * inv) * scale);
}

// ---------------------------------------------------------------------------
// MFMA conv: per-image GEMM Y[co][hw] = sum_k Wq[co][k] * B[k][hw]
// Tile 128(M) x 64(N), BK=32, 4 waves each 32x64. A direct from global,
// B double-buffered in LDS [hw][k] (stride 40 bf16 -> 2-way conflicts only).
// ---------------------------------------------------------------------------
template <int KDIM, bool IS3X3, typename TIN, typename TOUT>
__global__ __launch_bounds__(256) void conv_mfma(
    const TIN* __restrict__ X, const ushort* __restrict__ Wq,
    TOUT* __restrict__ Y, int M)
{
    constexpr int CIN = IS3X3 ? KDIM / 9 : KDIM;
    constexpr int NKT = KDIM / 32;
    __shared__ ushort Bs[2][64][40];

    const int n    = blockIdx.z;
    const int co0  = blockIdx.y * 128;
    const int hw0  = blockIdx.x * 64;
    const int tid  = threadIdx.x;
    const int lane = tid & 63;
    const int wv   = tid >> 6;

    const TIN* __restrict__ Xn = X + (size_t)n * CIN * IMG_HW;

    f32x4 acc[2][4];
#pragma unroll
    for (int i = 0; i < 2; ++i)
#pragma unroll
        for (int j = 0; j < 4; ++j)
            acc[i][j] = (f32x4)(0.f);

    ushort su[8];

    // ---- staging: load phase (global -> regs) ----
    auto stage_load = [&](int kt) {
        const int k0 = kt * 32;
        if constexpr (IS3X3) {
            const int cil = tid >> 3, hwo = (tid & 7) * 8;
            const int r  = kt >> 2;
            const int ci = (kt & 3) * 32 + cil;
            const int dh = r / 3 - 1, dw = r - (r / 3) * 3 - 1;
            const ushort* __restrict__ base = (const ushort*)Xn + ci * IMG_HW;
#pragma unroll
            for (int e = 0; e < 8; ++e) {
                int hw = hw0 + hwo + e;
                ushort val = 0;
                if (hw < IMG_HW) {
                    int h = hw / IMG_W;
                    int w = hw - h * IMG_W;
                    int h2 = h + dh, w2 = w + dw;
                    if ((unsigned)h2 < IMG_W && (unsigned)w2 < IMG_W)
                        val = base[h2 * IMG_W + w2];
                }
                su[e] = val;
            }
        } else if constexpr (sizeof(TIN) == 4) {   // fp32 input (conv1)
            const int cib = tid >> 4, hwq = (tid & 15) * 4;
            const bool v = (hw0 + hwq) < IMG_HW;
#pragma unroll
            for (int p = 0; p < 2; ++p) {
                float4 f = make_float4(0.f, 0.f, 0.f, 0.f);
                if (v)
                    f = *reinterpret_cast<const float4*>(
                        (const float*)Xn + (size_t)(k0 + cib + p * 16) * IMG_HW
                        + hw0 + hwq);
                su[p * 4 + 0] = f2bf(f.x);
                su[p * 4 + 1] = f2bf(f.y);
                su[p * 4 + 2] = f2bf(f.z);
                su[p * 4 + 3] = f2bf(f.w);
            }
        } else {                                    // bf16 input (conv3)
            const int cil = tid >> 3, hwo = (tid & 7) * 8;
            uint4 u = make_uint4(0, 0, 0, 0);
            if ((hw0 + hwo) < IMG_HW)
                u = *reinterpret_cast<const uint4*>(
                    (const ushort*)Xn + (size_t)(k0 + cil) * IMG_HW + hw0 + hwo);
            const ushort* p = (const ushort*)&u;
#pragma unroll
            for (int e = 0; e < 8; ++e) su[e] = p[e];
        }
    };

    // ---- staging: write phase (regs -> LDS) ----
    auto stage_write = [&](int kt) {
        const int buf = kt & 1;
        if constexpr (!IS3X3 && sizeof(TIN) == 4) {
            const int cib = tid >> 4, hwq = (tid & 15) * 4;
#pragma unroll
            for (int p = 0; p < 2; ++p)
#pragma unroll
                for (int e = 0; e < 4; ++e)
                    Bs[buf][hwq + e][cib + p * 16] = su[p * 4 + e];
        } else {
            const int cil = tid >> 3, hwo = (tid & 7) * 8;
#pragma unroll
            for (int e = 0; e < 8; ++e)
                Bs[buf][hwo + e][cil] = su[e];
        }
    };

    const int arow = co0 + wv * 32 + (lane & 15);
    const int akb  = (lane >> 4) * 8;
    auto loadA = [&](int kt, bf16x8* a) {
        const int k0 = kt * 32;
        a[0] = *reinterpret_cast<const bf16x8*>(
            &Wq[(size_t)arow * KDIM + k0 + akb]);
        a[1] = *reinterpret_cast<const bf16x8*>(
            &Wq[(size_t)(arow + 16) * KDIM + k0 + akb]);
    };

    bf16x8 a_cur[2], a_nxt[2];

    stage_load(0);
    loadA(0, a_cur);
    stage_write(0);
    __syncthreads();

    const int bn_ = lane & 15;
    const int bkb = (lane >> 4) * 8;

    for (int kt = 0; kt < NKT; ++kt) {
        const bool more = (kt + 1) < NKT;
        if (more) { stage_load(kt + 1); loadA(kt + 1, a_nxt); }

        const int buf = kt & 1;
#pragma unroll
        for (int fj = 0; fj < 4; ++fj) {
            bf16x8 b = *reinterpret_cast<const bf16x8*>(
                &Bs[buf][bn_ + fj * 16][bkb]);
            acc[0][fj] = __builtin_amdgcn_mfma_f32_16x16x32_bf16(
                a_cur[0], b, acc[0][fj], 0, 0, 0);
            acc[1][fj] = __builtin_amdgcn_mfma_f32_16x16x32_bf16(
                a_cur[1], b, acc[1][fj], 0, 0, 0);
        }
        if (more) {
            stage_write(kt + 1);
            a_cur[0] = a_nxt[0];
            a_cur[1] = a_nxt[1];
        }
        __syncthreads();
    }

    // epilogue: D[row=(l>>4)*4+r][col=l&15]
#pragma unroll
    for (int fi = 0; fi < 2; ++fi) {
#pragma unroll
        for (int fj = 0; fj < 4; ++fj) {
            int co = co0 + wv * 32 + fi * 16 + (lane >> 4) * 4;
            int hw = hw0 + fj * 16 + (lane & 15);
            if (hw < IMG_HW) {
#pragma unroll
                for (int r = 0; r < 4; ++r) {
                    float v = acc[fi][fj][r];
                    TOUT* dst = Y + ((size_t)n * M + co + r) * IMG_HW + hw;
                    if constexpr (sizeof(TOUT) == 2)
                        *dst = f2bf(v);
                    else
                        *dst = v;
                }
            }
        }
    }
}

// ---------------------------------------------------------------------------
// per-channel stats on bf16 tensor [NB][C][784], double accum, deterministic
// ---------------------------------------------------------------------------
__global__ __launch_bounds__(256) void stats_bf16(
    const ushort* __restrict__ Y, int C,
    float* __restrict__ mean, float* __restrict__ var)
{
    const int c = blockIdx.x;
    const int total = NB * IMG_HW;
    double s = 0.0, s2 = 0.0;
    for (int i = threadIdx.x; i < NB * 98; i += 256) {
        int n  = i / 98;
        int r8 = i - n * 98;
        uint4 v = *reinterpret_cast<const uint4*>(
            Y + ((size_t)n * C + c) * IMG_HW + r8 * 8);
        const ushort* u = (const ushort*)&v;
#pragma unroll
        for (int e = 0; e < 8; ++e) {
            float f = bf2f(u[e]);
            s  += f;
            s2 += (double)f * f;
        }
    }
#pragma unroll
    for (int off = 32; off > 0; off >>= 1) {
        s  += __shfl_down(s, off, 64);
        s2 += __shfl_down(s2, off, 64);
    }
    __shared__ double sd[4], sd2[4];
    int lane = threadIdx.x & 63, wid = threadIdx.x >> 6;
    if (lane == 0) { sd[wid] = s; sd2[wid] = s2; }
    __syncthreads();
    if (threadIdx.x == 0) {
        double ts = sd[0] + sd[1] + sd[2] + sd[3];
        double ts2 = sd2[0] + sd2[1] + sd2[2] + sd2[3];
        double m = ts / total;
        mean[c] = (float)m;
        var[c]  = (float)(ts2 / total - m * m);
    }
}

// ---------------------------------------------------------------------------
// in-place BN+ReLU on bf16 tensor (8 elems/thread)
// ---------------------------------------------------------------------------
__global__ void bn_relu_bf16(ushort* __restrict__ Y,
    const float* __restrict__ mean, const float* __restrict__ var,
    const float* __restrict__ gamma, const float* __restrict__ beta,
    int C, int total8)
{
    int i = blockIdx.x * blockDim.x + threadIdx.x;
    if (i >= total8) return;
    int c = (i / 98) % C;
    float m  = mean[c];
    float rs = rsqrtf(var[c] + BN_EPS) * gamma[c];
    float b  = beta[c];
    uint4 v = reinterpret_cast<uint4*>(Y)[i];
    ushort* u = (ushort*)&v;
#pragma unroll
    for (int e = 0; e < 8; ++e) {
        float f = bf2f(u[e]);
        f = fmaxf(fmaf(f - m, rs, b), 0.f);
        u[e] = f2bf(f);
    }
    reinterpret_cast<uint4*>(Y)[i] = v;
}

// ---------------------------------------------------------------------------
// fp32 stats (for conv3 output in d_out)
// ---------------------------------------------------------------------------
__global__ __launch_bounds__(1024) void stats_kernel(
    const float* __restrict__ Y, int C,
    float* __restrict__ mean, float* __restrict__ var)
{
    const int c = blockIdx.x;
    const int total = NB * IMG_HW;
    double s = 0.0, s2 = 0.0;
    for (int i = threadIdx.x; i < total; i += blockDim.x) {
        int n  = i / IMG_HW;
        int hw = i - n * IMG_HW;
        float v = Y[((size_t)n * C + c) * IMG_HW + hw];
        s  += v;
        s2 += (double)v * v;
    }
#pragma unroll
    for (int off = 32; off > 0; off >>= 1) {
        s  += __shfl_down(s, off, 64);
        s2 += __shfl_down(s2, off, 64);
    }
    __shared__ double sd[16], sd2[16];
    int lane = threadIdx.x & 63, wid = threadIdx.x >> 6;
    if (lane == 0) { sd[wid] = s; sd2[wid] = s2; }
    __syncthreads();
    if (threadIdx.x == 0) {
        int nw = blockDim.x >> 6;
        double ts = 0.0, ts2 = 0.0;
        for (int i = 0; i < nw; ++i) { ts += sd[i]; ts2 += sd2[i]; }
        double m = ts / total;
        mean[c] = (float)m;
        var[c]  = (float)(ts2 / total - m * m);
    }
}

// ---------------------------------------------------------------------------
// final: out = relu(BN3(out) + x), in-place fp32
// ---------------------------------------------------------------------------
__global__ void bn_add_relu_kernel(float* __restrict__ Y,
    const float* __restrict__ X,
    const float* __restrict__ mean, const float* __restrict__ var,
    const float* __restrict__ gamma, const float* __restrict__ beta,
    int C, int total4)
{
    int stride = gridDim.x * blockDim.x;
    for (int i = blockIdx.x * blockDim.x + threadIdx.x; i < total4; i += stride) {
        int c = (i / (IMG_HW / 4)) % C;
        float m  = mean[c];
        float rs = rsqrtf(var[c] + BN_EPS) * gamma[c];
        float b  = beta[c];
        float4 v  = reinterpret_cast<float4*>(Y)[i];
        float4 xv = reinterpret_cast<const float4*>(X)[i];
        v.x = fmaxf(fmaf(v.x - m, rs, b) + xv.x, 0.f);
        v.y = fmaxf(fmaf(v.y - m, rs, b) + xv.y, 0.f);
        v.z = fmaxf(fmaf(v.z - m, rs, b) + xv.z, 0.f);
        v.w = fmaxf(fmaf(v.w - m, rs, b) + xv.w, 0.f);
        reinterpret_cast<float4*>(Y)[i] = v;
    }
}

// ---------------------------------------------------------------------------
extern "C" void kernel_launch(void* const* d_in, const int* in_sizes, int n_in,
                              void* d_out, int out_size, void* d_ws, size_t ws_size,
                              hipStream_t stream)
{
    const float* x   = (const float*)d_in[0];
    const float* w1  = (const float*)d_in[1];
    const float* g1  = (const float*)d_in[3];
    const float* be1 = (const float*)d_in[4];
    const float* w2  = (const float*)d_in[5];
    const float* g2  = (const float*)d_in[7];
    const float* be2 = (const float*)d_in[8];
    const float* w3  = (const float*)d_in[9];
    const float* g3  = (const float*)d_in[11];
    const float* be3 = (const float*)d_in[12];
    // biases b1,b2,b3 cancel exactly through training-mode BN -> unused
    float* out = (float*)d_out;

    char* wsb = (char*)d_ws;
    unsigned int* amax = (unsigned int*)wsb;
    float* stat  = (float*)(wsb + 256);
    float* mean1 = stat;        float* var1 = stat + 512;
    float* mean2 = stat + 1024; float* var2 = stat + 1536;
    float* mean3 = stat + 2048; float* var3 = stat + 2560;
    ushort* Wq1 = (ushort*)(wsb + 16384);
    ushort* Wq2 = Wq1 + 65536;                 // 128*1152
    ushort* Wq3 = Wq2 + 147456;                // 512*128
    ushort* y1  = Wq3 + 65536;                 // 64*128*784 bf16
    ushort* y2  = y1 + (size_t)NB * 128 * IMG_HW;

    hipMemsetAsync(amax, 0, 3 * sizeof(unsigned int), stream);

    absmax_kernel<<<64, 256, 0, stream>>>(w1, 128 * 512, amax + 0);
    absmax_kernel<<<64, 256, 0, stream>>>(w2, 128 * 128 * 9, amax + 1);
    absmax_kernel<<<64, 256, 0, stream>>>(w3, 512 * 128, amax + 2);

    prequant_kernel<<<256, 256, 0, stream>>>(w1, 128 * 512, amax + 0, Wq1);
    prequant_w2_kernel<<<576, 256, 0, stream>>>(w2, amax + 1, Wq2);
    prequant_kernel<<<256, 256, 0, stream>>>(w3, 512 * 128, amax + 2, Wq3);

    // conv1: 512 -> 128, input fp32 x, output bf16 y1
    conv_mfma<512, false, float, ushort>
        <<<dim3(13, 1, NB), 256, 0, stream>>>(x, Wq1, y1, 128);
    stats_bf16<<<128, 256, 0, stream>>>(y1, 128, mean1, var1);
    bn_relu_bf16<<<3136, 256, 0, stream>>>(y1, mean1, var1, g1, be1, 128,
                                           NB * 128 * 98);

    // conv2: 3x3, 128 -> 128, bf16 in/out
    conv_mfma<1152, true, ushort, ushort>
        <<<dim3(13, 1, NB), 256, 0, stream>>>(y1, Wq2, y2, 128);
    stats_bf16<<<128, 256, 0, stream>>>(y2, 128, mean2, var2);
    bn_relu_bf16<<<3136, 256, 0, stream>>>(y2, mean2, var2, g2, be2, 128,
                                           NB * 128 * 98);

    // conv3: 128 -> 512, bf16 in, fp32 out (pre-BN) into d_out
    conv_mfma<128, false, ushort, float>
        <<<dim3(13, 4, NB), 256, 0, stream>>>(y2, Wq3, out, 512);
    stats_kernel<<<512, 1024, 0, stream>>>(out, 512, mean3, var3);
    bn_add_relu_kernel<<<2048, 256, 0, stream>>>(out, x, mean3, var3, g3, be3,
                                                 512, NB * 512 * (IMG_HW / 4));
}

// Round 3
// 179.769 us; speedup vs baseline: 3.6147x; 1.4935x over previous
//
#include <hip/hip_runtime.h>
#include <hip/hip_bf16.h>
#include <math.h>

#define HW 784
#define IW 28
#define NB 64
#define BN_EPS 1e-5f

typedef __attribute__((ext_vector_type(8))) short bf16x8;
typedef __attribute__((ext_vector_type(4))) float f32x4;

static __device__ __forceinline__ ushort f2bf(float f) {
    __hip_bfloat16 h = __float2bfloat16(f);
    return *reinterpret_cast<ushort*>(&h);
}
static __device__ __forceinline__ float bf2f(ushort u) {
    return __uint_as_float(((unsigned)u) << 16);
}

// ---------------------------------------------------------------------------
// absmax -> uint-encoded float (bitwise atomicMax valid for non-negative)
// ---------------------------------------------------------------------------
__global__ void absmax_kernel(const float* __restrict__ w, int n,
                              unsigned int* __restrict__ slot) {
    float m = 0.f;
    for (int i = blockIdx.x * blockDim.x + threadIdx.x; i < n;
         i += gridDim.x * blockDim.x)
        m = fmaxf(m, fabsf(w[i]));
#pragma unroll
    for (int off = 32; off > 0; off >>= 1)
        m = fmaxf(m, __shfl_down(m, off, 64));
    __shared__ float sm[4];
    int lane = threadIdx.x & 63, wid = threadIdx.x >> 6;
    if (lane == 0) sm[wid] = m;
    __syncthreads();
    if (threadIdx.x == 0) {
        float b = fmaxf(fmaxf(sm[0], sm[1]), fmaxf(sm[2], sm[3]));
        atomicMax(slot, __float_as_uint(b));
    }
}

__global__ void prequant_kernel(const float* __restrict__ w, int n,
                                const unsigned int* __restrict__ amax,
                                ushort* __restrict__ out) {
    float am = __uint_as_float(*amax);
    float scale = am * (1.0f / 127.0f);
    float inv   = 127.0f / am;
    for (int i = blockIdx.x * blockDim.x + threadIdx.x; i < n;
         i += gridDim.x * blockDim.x)
        out[i] = f2bf(rintf(w[i] * inv) * scale);
}

// w2 [co][ci][r=kh*3+kw] -> bf16 [co][r*128+ci]
__global__ void prequant_w2_kernel(const float* __restrict__ w,
                                   const unsigned int* __restrict__ amax,
                                   ushort* __restrict__ out) {
    float am = __uint_as_float(*amax);
    float scale = am * (1.0f / 127.0f);
    float inv   = 127.0f / am;
    int i = blockIdx.x * blockDim.x + threadIdx.x;
    if (i >= 128 * 128 * 9) return;
    int co  = i / 1152;
    int rem = i - co * 1152;
    int ci  = rem / 9;
    int r   = rem - ci * 9;
    out[co * 1152 + r * 128 + ci] = f2bf(rintf(w[i] * inv) * scale);
}

// ---------------------------------------------------------------------------
// shared epilogue: write transposed bf16 [hw][C] + per-channel partial stats
// wave covers 32 co (2 M-frags) x 112 hw (7 N-frags)
// ---------------------------------------------------------------------------
__device__ __forceinline__ void epi_t(
    f32x4 (*acc)[7], ushort* __restrict__ yt_img, float* __restrict__ part,
    int C, int pb, int co0, int colane, int lanehi)
{
#pragma unroll
    for (int fi = 0; fi < 2; ++fi) {
#pragma unroll
        for (int j = 0; j < 7; ++j) {
            int hw = j * 16 + colane;
            int co = co0 + fi * 16 + lanehi * 4;
            ushort4 u;
            u.x = f2bf(acc[fi][j][0]); u.y = f2bf(acc[fi][j][1]);
            u.z = f2bf(acc[fi][j][2]); u.w = f2bf(acc[fi][j][3]);
            *reinterpret_cast<ushort4*>(&yt_img[(size_t)hw * C + co]) = u;
        }
        float s[4] = {0, 0, 0, 0}, q[4] = {0, 0, 0, 0};
#pragma unroll
        for (int j = 0; j < 7; ++j)
#pragma unroll
            for (int r = 0; r < 4; ++r) {
                float v = acc[fi][j][r];
                s[r] += v; q[r] += v * v;
            }
#pragma unroll
        for (int m = 1; m < 16; m <<= 1)
#pragma unroll
            for (int r = 0; r < 4; ++r) {
                s[r] += __shfl_xor(s[r], m, 64);
                q[r] += __shfl_xor(q[r], m, 64);
            }
        if (colane == 0) {
#pragma unroll
            for (int r = 0; r < 4; ++r) {
                int co = co0 + fi * 16 + lanehi * 4 + r;
                part[(size_t)co * 448 + pb]       = s[r];
                part[(size_t)(C + co) * 448 + pb] = q[r];
            }
        }
    }
}

// NOTE: epilogue hw is tile-relative; yt_img must be pre-offset by hw-tile.

// ---------------------------------------------------------------------------
// conv1: 1x1, K=512, fp32 input x[n][ci][hw] -> y1t[n][hw][128co] bf16.
// Block 256thr = 4 waves x 32co. hw-tile 112 (4 image rows). LDS double-buf
// [112][40] per K-chunk of 32ci. Coalesced f32 loads, ushort4 LDS writes.
// ---------------------------------------------------------------------------
__global__ __launch_bounds__(256, 2) void conv1_mfma(
    const float* __restrict__ X, const ushort* __restrict__ Wq,
    ushort* __restrict__ y1t, float* __restrict__ part)
{
    __shared__ ushort lds[2][112 * 40];
    const int n = blockIdx.z, hwt = blockIdx.x;
    const int tid = threadIdx.x, lane = tid & 63, wv = tid >> 6;
    const int colane = lane & 15, lanehi = lane >> 4, klane = lanehi * 8;
    const float* __restrict__ Xn = X + (size_t)n * 512 * HW + hwt * 112;

    int s_hw[4], s_cg[4];
#pragma unroll
    for (int it = 0; it < 4; ++it) {
        int idx = tid + it * 256;
        s_hw[it] = idx % 112; s_cg[it] = idx / 112;   // 896 total (112hw x 8grp)
    }
    float4 rv[4];

    auto sload = [&](int kt) {
#pragma unroll
        for (int it = 0; it < 4; ++it) {
            if (it == 3 && tid >= 128) continue;
            const float* xp = Xn + (size_t)(kt * 32 + s_cg[it] * 4) * HW + s_hw[it];
            rv[it].x = xp[0];
            rv[it].y = xp[HW];
            rv[it].z = xp[2 * HW];
            rv[it].w = xp[3 * HW];
        }
    };
    auto swrite = [&](int b) {
#pragma unroll
        for (int it = 0; it < 4; ++it) {
            if (it == 3 && tid >= 128) continue;
            ushort4 u;
            u.x = f2bf(rv[it].x); u.y = f2bf(rv[it].y);
            u.z = f2bf(rv[it].z); u.w = f2bf(rv[it].w);
            *reinterpret_cast<ushort4*>(&lds[b][s_hw[it] * 40 + s_cg[it] * 4]) = u;
        }
    };

    f32x4 acc[2][7];
#pragma unroll
    for (int i = 0; i < 2; ++i)
#pragma unroll
        for (int j = 0; j < 7; ++j) acc[i][j] = (f32x4)(0.f);

    const ushort* A0 = Wq + (size_t)(wv * 32 + colane) * 512 + klane;

    sload(0); swrite(0); __syncthreads();
    for (int kt = 0; kt < 16; ++kt) {
        if (kt < 15) sload(kt + 1);
        const int b = kt & 1;
        bf16x8 a0 = *reinterpret_cast<const bf16x8*>(A0 + kt * 32);
        bf16x8 a1 = *reinterpret_cast<const bf16x8*>(A0 + 16 * 512 + kt * 32);
#pragma unroll
        for (int j = 0; j < 7; ++j) {
            bf16x8 bb = *reinterpret_cast<const bf16x8*>(
                &lds[b][(j * 16 + colane) * 40 + klane]);
            acc[0][j] = __builtin_amdgcn_mfma_f32_16x16x32_bf16(a0, bb, acc[0][j], 0, 0, 0);
            acc[1][j] = __builtin_amdgcn_mfma_f32_16x16x32_bf16(a1, bb, acc[1][j], 0, 0, 0);
        }
        if (kt < 15) swrite(b ^ 1);
        __syncthreads();
    }
    epi_t(acc, y1t + (size_t)n * HW * 128 + (size_t)hwt * 112 * 128, part,
          128, n * 7 + hwt, wv * 32, colane, lanehi);
}

// ---------------------------------------------------------------------------
// conv2: 3x3 pad1, K=1152, y1t[n][hw][128] -> y2t[n][hw][128].
// Halo tile in LDS: per ci-pair-chunk (64ci) rows h0-1..h0+4 x w -1..28,
// layout [cc][rr][ww][40pad]. Shift (dh,dw) = uniform scalar LDS delta.
// 2 chunk-pairs, 2 barriers, reg-prefetch of second pair.
// ---------------------------------------------------------------------------
__global__ __launch_bounds__(256, 2) void conv2_mfma(
    const ushort* __restrict__ y1t, const ushort* __restrict__ Wq,
    ushort* __restrict__ y2t, float* __restrict__ part)
{
    __shared__ ushort lds[2][2 * 6 * 30 * 40];   // 2 bufs x 2 chunks x 7200
    const int n = blockIdx.z, hwt = blockIdx.x;
    const int tid = threadIdx.x, lane = tid & 63, wv = tid >> 6;
    const int colane = lane & 15, lanehi = lane >> 4, klane = lanehi * 8;
    const size_t noff = (size_t)n * HW * 128;
    const int h0 = hwt * 4;

    // direct stage of chunk-pair p into buffer b (1440 16B-slots)
    auto stage = [&](int p, int b) {
        for (int s = tid; s < 1440; s += 256) {
            int rr = s / 240, rem = s - rr * 240, ww = rem >> 3, sl = rem & 7;
            int cc = sl >> 2, g = sl & 3;
            int h = h0 - 1 + rr, w = ww - 1;
            uint4 v = make_uint4(0, 0, 0, 0);
            if ((unsigned)h < IW && (unsigned)w < IW)
                v = *reinterpret_cast<const uint4*>(
                    &y1t[noff + (size_t)(h * IW + w) * 128 + (2 * p + cc) * 32 + g * 8]);
            *reinterpret_cast<uint4*>(&lds[b][((cc * 6 + rr) * 30 + ww) * 40 + g * 8]) = v;
        }
    };

    int base[7];
#pragma unroll
    for (int j = 0; j < 7; ++j) {
        int hwl = j * 16 + colane;
        int hl = hwl / 28, wl = hwl - hl * 28;
        base[j] = ((hl + 1) * 30 + (wl + 1)) * 40 + klane;
    }

    f32x4 acc[2][7];
#pragma unroll
    for (int i = 0; i < 2; ++i)
#pragma unroll
        for (int j = 0; j < 7; ++j) acc[i][j] = (f32x4)(0.f);

    const ushort* A0 = Wq + (size_t)(wv * 32 + colane) * 1152 + klane;

    auto compute = [&](int p, int b) {
        for (int r = 0; r < 9; ++r) {
            const int dh = r / 3 - 1, dw = r - (r / 3) * 3 - 1;
            const int delta = (dh * 30 + dw) * 40;
#pragma unroll
            for (int cc = 0; cc < 2; ++cc) {
                bf16x8 a0 = *reinterpret_cast<const bf16x8*>(
                    A0 + r * 128 + (2 * p + cc) * 32);
                bf16x8 a1 = *reinterpret_cast<const bf16x8*>(
                    A0 + 16 * 1152 + r * 128 + (2 * p + cc) * 32);
                const ushort* L = &lds[b][cc * 7200];
#pragma unroll
                for (int j = 0; j < 7; ++j) {
                    bf16x8 bb = *reinterpret_cast<const bf16x8*>(&L[base[j] + delta]);
                    acc[0][j] = __builtin_amdgcn_mfma_f32_16x16x32_bf16(a0, bb, acc[0][j], 0, 0, 0);
                    acc[1][j] = __builtin_amdgcn_mfma_f32_16x16x32_bf16(a1, bb, acc[1][j], 0, 0, 0);
                }
            }
        }
    };

    stage(0, 0);
    __syncthreads();

    // prefetch pair 1 to regs while computing pair 0
    uint4 pv[6];
#pragma unroll
    for (int it = 0; it < 6; ++it) {
        int s = tid + it * 256;
        if (it == 5 && tid >= 160) continue;
        int rr = s / 240, rem = s - rr * 240, ww = rem >> 3, sl = rem & 7;
        int cc = sl >> 2, g = sl & 3;
        int h = h0 - 1 + rr, w = ww - 1;
        uint4 v = make_uint4(0, 0, 0, 0);
        if ((unsigned)h < IW && (unsigned)w < IW)
            v = *reinterpret_cast<const uint4*>(
                &y1t[noff + (size_t)(h * IW + w) * 128 + (2 + cc) * 32 + g * 8]);
        pv[it] = v;
    }

    compute(0, 0);

#pragma unroll
    for (int it = 0; it < 6; ++it) {
        int s = tid + it * 256;
        if (it == 5 && tid >= 160) continue;
        int rr = s / 240, rem = s - rr * 240, ww = rem >> 3, sl = rem & 7;
        int cc = sl >> 2, g = sl & 3;
        *reinterpret_cast<uint4*>(&lds[1][((cc * 6 + rr) * 30 + ww) * 40 + g * 8]) = pv[it];
    }
    __syncthreads();
    compute(1, 1);

    epi_t(acc, y2t + noff + (size_t)hwt * 112 * 128, part,
          128, n * 7 + hwt, wv * 32, colane, lanehi);
}

// ---------------------------------------------------------------------------
// conv3: 1x1, K=128, y2t[n][hw][128] -> y3 [n][co][hw] (bf16 or f32).
// No LDS: B-fragments direct from global (L1-resident, shared by 4 waves).
// ---------------------------------------------------------------------------
template <int BF16OUT>
__global__ __launch_bounds__(256, 2) void conv3_mfma(
    const ushort* __restrict__ y2t, const ushort* __restrict__ Wq,
    void* __restrict__ yout, float* __restrict__ part)
{
    const int n = blockIdx.z, hwt = blockIdx.x, cot = blockIdx.y;
    const int tid = threadIdx.x, lane = tid & 63, wv = tid >> 6;
    const int colane = lane & 15, lanehi = lane >> 4, klane = lanehi * 8;
    const int co0 = cot * 128 + wv * 32;
    const size_t noff = (size_t)n * HW * 128;

    int hwj[7];
#pragma unroll
    for (int j = 0; j < 7; ++j) hwj[j] = hwt * 112 + j * 16 + colane;

    f32x4 acc[2][7];
#pragma unroll
    for (int i = 0; i < 2; ++i)
#pragma unroll
        for (int j = 0; j < 7; ++j) acc[i][j] = (f32x4)(0.f);

    const ushort* A0 = Wq + (size_t)(co0 + colane) * 128 + klane;
    const ushort* B0 = y2t + noff + klane;

#pragma unroll
    for (int kt = 0; kt < 4; ++kt) {
        bf16x8 a0 = *reinterpret_cast<const bf16x8*>(A0 + kt * 32);
        bf16x8 a1 = *reinterpret_cast<const bf16x8*>(A0 + 16 * 128 + kt * 32);
#pragma unroll
        for (int j = 0; j < 7; ++j) {
            bf16x8 bb = *reinterpret_cast<const bf16x8*>(
                &B0[(size_t)hwj[j] * 128 + kt * 32]);
            acc[0][j] = __builtin_amdgcn_mfma_f32_16x16x32_bf16(a0, bb, acc[0][j], 0, 0, 0);
            acc[1][j] = __builtin_amdgcn_mfma_f32_16x16x32_bf16(a1, bb, acc[1][j], 0, 0, 0);
        }
    }

#pragma unroll
    for (int fi = 0; fi < 2; ++fi) {
#pragma unroll
        for (int j = 0; j < 7; ++j) {
            int cob = co0 + fi * 16 + lanehi * 4;
            int hw = hwj[j];
#pragma unroll
            for (int r = 0; r < 4; ++r) {
                float v = acc[fi][j][r];
                if (BF16OUT)
                    ((ushort*)yout)[((size_t)n * 512 + cob + r) * HW + hw] = f2bf(v);
                else
                    ((float*)yout)[((size_t)n * 512 + cob + r) * HW + hw] = v;
            }
        }
        float s[4] = {0, 0, 0, 0}, q[4] = {0, 0, 0, 0};
#pragma unroll
        for (int j = 0; j < 7; ++j)
#pragma unroll
            for (int r = 0; r < 4; ++r) {
                float v = acc[fi][j][r];
                s[r] += v; q[r] += v * v;
            }
#pragma unroll
        for (int m = 1; m < 16; m <<= 1)
#pragma unroll
            for (int r = 0; r < 4; ++r) {
                s[r] += __shfl_xor(s[r], m, 64);
                q[r] += __shfl_xor(q[r], m, 64);
            }
        if (colane == 0) {
#pragma unroll
            for (int r = 0; r < 4; ++r) {
                int co = co0 + fi * 16 + lanehi * 4 + r;
                part[(size_t)co * 448 + (n * 7 + hwt)]         = s[r];
                part[(size_t)(512 + co) * 448 + (n * 7 + hwt)] = q[r];
            }
        }
    }
}

// ---------------------------------------------------------------------------
// finalize: partials[2C][448] -> rs[c], sh[c]  (BN affine coefficients)
// ---------------------------------------------------------------------------
__global__ void finalize_stats(const float* __restrict__ part, int C,
    const float* __restrict__ gamma, const float* __restrict__ beta,
    float* __restrict__ rs, float* __restrict__ sh)
{
    int c = blockIdx.x, lane = threadIdx.x;
    double s = 0.0, s2 = 0.0;
    for (int i = lane; i < 448; i += 64) {
        s  += part[(size_t)c * 448 + i];
        s2 += part[(size_t)(C + c) * 448 + i];
    }
#pragma unroll
    for (int m = 1; m < 64; m <<= 1) {
        s  += __shfl_xor(s, m, 64);
        s2 += __shfl_xor(s2, m, 64);
    }
    if (lane == 0) {
        double tot = (double)NB * HW;
        double mean = s / tot;
        float var = (float)(s2 / tot - mean * mean);
        float r = rsqrtf(var + BN_EPS) * gamma[c];
        rs[c] = r;
        sh[c] = beta[c] - (float)mean * r;
    }
}

// ---------------------------------------------------------------------------
// in-place BN+ReLU on transposed bf16 [n][hw][128]
// ---------------------------------------------------------------------------
__global__ void bn_relu_t(ushort* __restrict__ yt,
    const float* __restrict__ rs, const float* __restrict__ sh, int total16)
{
    int i = blockIdx.x * blockDim.x + threadIdx.x;
    if (i >= total16) return;
    int c0 = (i & 15) * 8;
    uint4 v = reinterpret_cast<uint4*>(yt)[i];
    float4 ra = *reinterpret_cast<const float4*>(&rs[c0]);
    float4 rb = *reinterpret_cast<const float4*>(&rs[c0 + 4]);
    float4 sa = *reinterpret_cast<const float4*>(&sh[c0]);
    float4 sb = *reinterpret_cast<const float4*>(&sh[c0 + 4]);
    ushort* u = (ushort*)&v;
    u[0] = f2bf(fmaxf(fmaf(bf2f(u[0]), ra.x, sa.x), 0.f));
    u[1] = f2bf(fmaxf(fmaf(bf2f(u[1]), ra.y, sa.y), 0.f));
    u[2] = f2bf(fmaxf(fmaf(bf2f(u[2]), ra.z, sa.z), 0.f));
    u[3] = f2bf(fmaxf(fmaf(bf2f(u[3]), ra.w, sa.w), 0.f));
    u[4] = f2bf(fmaxf(fmaf(bf2f(u[4]), rb.x, sb.x), 0.f));
    u[5] = f2bf(fmaxf(fmaf(bf2f(u[5]), rb.y, sb.y), 0.f));
    u[6] = f2bf(fmaxf(fmaf(bf2f(u[6]), rb.z, sb.z), 0.f));
    u[7] = f2bf(fmaxf(fmaf(bf2f(u[7]), rb.w, sb.w), 0.f));
    reinterpret_cast<uint4*>(yt)[i] = v;
}

// ---------------------------------------------------------------------------
// final: out = relu(BN3(y3) + x)
// ---------------------------------------------------------------------------
__global__ void final_f32(float* __restrict__ out, const float* __restrict__ x,
    const float* __restrict__ rs, const float* __restrict__ sh)
{
    int i = blockIdx.x * blockDim.x + threadIdx.x;
    if (i >= NB * 512 * (HW / 4)) return;
    int c = (i / (HW / 4)) & 511;
    float r = rs[c], s = sh[c];
    float4 v = reinterpret_cast<float4*>(out)[i];
    float4 xv = reinterpret_cast<const float4*>(x)[i];
    v.x = fmaxf(fmaf(v.x, r, s) + xv.x, 0.f);
    v.y = fmaxf(fmaf(v.y, r, s) + xv.y, 0.f);
    v.z = fmaxf(fmaf(v.z, r, s) + xv.z, 0.f);
    v.w = fmaxf(fmaf(v.w, r, s) + xv.w, 0.f);
    reinterpret_cast<float4*>(out)[i] = v;
}

__global__ void final_b16(float* __restrict__ out, const float* __restrict__ x,
    const ushort* __restrict__ y3,
    const float* __restrict__ rs, const float* __restrict__ sh)
{
    int i = blockIdx.x * blockDim.x + threadIdx.x;
    if (i >= NB * 512 * 98) return;
    int c = (i / 98) & 511;
    float r = rs[c], s = sh[c];
    uint4 yv = reinterpret_cast<const uint4*>(y3)[i];
    const ushort* u = (const ushort*)&yv;
    float4 x0 = reinterpret_cast<const float4*>(x)[2 * i];
    float4 x1 = reinterpret_cast<const float4*>(x)[2 * i + 1];
    float4 o0, o1;
    o0.x = fmaxf(fmaf(bf2f(u[0]), r, s) + x0.x, 0.f);
    o0.y = fmaxf(fmaf(bf2f(u[1]), r, s) + x0.y, 0.f);
    o0.z = fmaxf(fmaf(bf2f(u[2]), r, s) + x0.z, 0.f);
    o0.w = fmaxf(fmaf(bf2f(u[3]), r, s) + x0.w, 0.f);
    o1.x = fmaxf(fmaf(bf2f(u[4]), r, s) + x1.x, 0.f);
    o1.y = fmaxf(fmaf(bf2f(u[5]), r, s) + x1.y, 0.f);
    o1.z = fmaxf(fmaf(bf2f(u[6]), r, s) + x1.z, 0.f);
    o1.w = fmaxf(fmaf(bf2f(u[7]), r, s) + x1.w, 0.f);
    reinterpret_cast<float4*>(out)[2 * i] = o0;
    reinterpret_cast<float4*>(out)[2 * i + 1] = o1;
}

// ---------------------------------------------------------------------------
extern "C" void kernel_launch(void* const* d_in, const int* in_sizes, int n_in,
                              void* d_out, int out_size, void* d_ws, size_t ws_size,
                              hipStream_t stream)
{
    const float* x   = (const float*)d_in[0];
    const float* w1  = (const float*)d_in[1];
    const float* g1  = (const float*)d_in[3];
    const float* be1 = (const float*)d_in[4];
    const float* w2  = (const float*)d_in[5];
    const float* g2  = (const float*)d_in[7];
    const float* be2 = (const float*)d_in[8];
    const float* w3  = (const float*)d_in[9];
    const float* g3  = (const float*)d_in[11];
    const float* be3 = (const float*)d_in[12];
    float* out = (float*)d_out;

    char* wsb = (char*)d_ws;
    unsigned int* amax = (unsigned int*)wsb;
    float* rs1 = (float*)(wsb + 1024);
    float* sh1 = (float*)(wsb + 1536);
    float* rs2 = (float*)(wsb + 2048);
    float* sh2 = (float*)(wsb + 2560);
    float* rs3 = (float*)(wsb + 3072);
    float* sh3 = (float*)(wsb + 5120);
    float* part1 = (float*)(wsb + 8192);      // [256][448]
    float* part2 = (float*)(wsb + 466944);    // [256][448]
    float* part3 = (float*)(wsb + 925696);    // [1024][448]
    ushort* Wq1 = (ushort*)(wsb + 2760704);
    ushort* Wq2 = (ushort*)(wsb + 2891776);
    ushort* Wq3 = (ushort*)(wsb + 3186688);
    ushort* y1t = (ushort*)(wsb + 3317760);
    ushort* y2t = (ushort*)(wsb + 16162816);
    ushort* y3b = (ushort*)(wsb + 29007872);  // only if ws is big enough

    const bool big = ws_size >= (size_t)82000000;

    hipMemsetAsync(amax, 0, 64, stream);

    absmax_kernel<<<64, 256, 0, stream>>>(w1, 128 * 512, amax + 0);
    absmax_kernel<<<64, 256, 0, stream>>>(w2, 128 * 128 * 9, amax + 1);
    absmax_kernel<<<64, 256, 0, stream>>>(w3, 512 * 128, amax + 2);

    prequant_kernel<<<256, 256, 0, stream>>>(w1, 128 * 512, amax + 0, Wq1);
    prequant_w2_kernel<<<576, 256, 0, stream>>>(w2, amax + 1, Wq2);
    prequant_kernel<<<256, 256, 0, stream>>>(w3, 512 * 128, amax + 2, Wq3);

    conv1_mfma<<<dim3(7, 1, NB), 256, 0, stream>>>(x, Wq1, y1t, part1);
    finalize_stats<<<128, 64, 0, stream>>>(part1, 128, g1, be1, rs1, sh1);
    bn_relu_t<<<3136, 256, 0, stream>>>(y1t, rs1, sh1, NB * HW * 16);

    conv2_mfma<<<dim3(7, 1, NB), 256, 0, stream>>>(y1t, Wq2, y2t, part2);
    finalize_stats<<<128, 64, 0, stream>>>(part2, 128, g2, be2, rs2, sh2);
    bn_relu_t<<<3136, 256, 0, stream>>>(y2t, rs2, sh2, NB * HW * 16);

    if (big) {
        conv3_mfma<1><<<dim3(7, 4, NB), 256, 0, stream>>>(y2t, Wq3, y3b, part3);
        finalize_stats<<<512, 64, 0, stream>>>(part3, 512, g3, be3, rs3, sh3);
        final_b16<<<12544, 256, 0, stream>>>(out, x, y3b, rs3, sh3);
    } else {
        conv3_mfma<0><<<dim3(7, 4, NB), 256, 0, stream>>>(y2t, Wq3, out, part3);
        finalize_stats<<<512, 64, 0, stream>>>(part3, 512, g3, be3, rs3, sh3);
        final_f32<<<25088, 256, 0, stream>>>(out, x, rs3, sh3);
    }
}

// Round 4
// 152.994 us; speedup vs baseline: 4.2473x; 1.1750x over previous
//
#include <hip/hip_runtime.h>
#include <hip/hip_bf16.h>
#include <math.h>

#define HW 784
#define IW 28
#define NB 64
#define BN_EPS 1e-5f

typedef __attribute__((ext_vector_type(8))) short bf16x8;
typedef __attribute__((ext_vector_type(4))) float f32x4;

static __device__ __forceinline__ ushort f2bf(float f) {
    __hip_bfloat16 h = __float2bfloat16(f);
    return *reinterpret_cast<ushort*>(&h);
}
static __device__ __forceinline__ float bf2f(ushort u) {
    return __uint_as_float(((unsigned)u) << 16);
}

// BN+ReLU on a packed 8-channel bf16 uint4, channels [c0..c0+8)
static __device__ __forceinline__ uint4 bn_pack(uint4 v,
    const float* __restrict__ rs, const float* __restrict__ sh, int c0)
{
    float4 ra = *reinterpret_cast<const float4*>(rs + c0);
    float4 rb = *reinterpret_cast<const float4*>(rs + c0 + 4);
    float4 sa = *reinterpret_cast<const float4*>(sh + c0);
    float4 sb = *reinterpret_cast<const float4*>(sh + c0 + 4);
    ushort* u = (ushort*)&v;
    u[0] = f2bf(fmaxf(fmaf(bf2f(u[0]), ra.x, sa.x), 0.f));
    u[1] = f2bf(fmaxf(fmaf(bf2f(u[1]), ra.y, sa.y), 0.f));
    u[2] = f2bf(fmaxf(fmaf(bf2f(u[2]), ra.z, sa.z), 0.f));
    u[3] = f2bf(fmaxf(fmaf(bf2f(u[3]), ra.w, sa.w), 0.f));
    u[4] = f2bf(fmaxf(fmaf(bf2f(u[4]), rb.x, sb.x), 0.f));
    u[5] = f2bf(fmaxf(fmaf(bf2f(u[5]), rb.y, sb.y), 0.f));
    u[6] = f2bf(fmaxf(fmaf(bf2f(u[6]), rb.z, sb.z), 0.f));
    u[7] = f2bf(fmaxf(fmaf(bf2f(u[7]), rb.w, sb.w), 0.f));
    return v;
}

// ---------------------------------------------------------------------------
// merged absmax for all 3 weight tensors (blockIdx.y = tensor id)
// ---------------------------------------------------------------------------
__global__ void absmax3_kernel(const float* __restrict__ w1,
                               const float* __restrict__ w2,
                               const float* __restrict__ w3,
                               unsigned int* __restrict__ slots) {
    const int t = blockIdx.y;
    const float* w = t == 0 ? w1 : (t == 1 ? w2 : w3);
    const int n = (t == 1) ? 147456 : 65536;
    float m = 0.f;
    for (int i = blockIdx.x * blockDim.x + threadIdx.x; i < n;
         i += gridDim.x * blockDim.x)
        m = fmaxf(m, fabsf(w[i]));
#pragma unroll
    for (int off = 32; off > 0; off >>= 1)
        m = fmaxf(m, __shfl_down(m, off, 64));
    __shared__ float sm[4];
    int lane = threadIdx.x & 63, wid = threadIdx.x >> 6;
    if (lane == 0) sm[wid] = m;
    __syncthreads();
    if (threadIdx.x == 0) {
        float b = fmaxf(fmaxf(sm[0], sm[1]), fmaxf(sm[2], sm[3]));
        atomicMax(slots + t, __float_as_uint(b));
    }
}

// ---------------------------------------------------------------------------
// merged prequant: w1,w3 same-layout; w2 -> [co][r*128+ci] transpose
// ---------------------------------------------------------------------------
__global__ void prequant3_kernel(const float* __restrict__ w1,
                                 const float* __restrict__ w2,
                                 const float* __restrict__ w3,
                                 const unsigned int* __restrict__ amax,
                                 ushort* __restrict__ o1,
                                 ushort* __restrict__ o2,
                                 ushort* __restrict__ o3) {
    const int t = blockIdx.y;
    const float* w = t == 0 ? w1 : (t == 1 ? w2 : w3);
    ushort* o = t == 0 ? o1 : (t == 1 ? o2 : o3);
    const int n = (t == 1) ? 147456 : 65536;
    float am = __uint_as_float(amax[t]);
    float scale = am * (1.0f / 127.0f);
    float inv   = 127.0f / am;
    for (int i = blockIdx.x * blockDim.x + threadIdx.x; i < n;
         i += gridDim.x * blockDim.x) {
        float q = rintf(w[i] * inv) * scale;
        if (t == 1) {
            int co  = i / 1152;
            int rem = i - co * 1152;
            int ci  = rem / 9;
            int r   = rem - ci * 9;
            o[co * 1152 + r * 128 + ci] = f2bf(q);
        } else {
            o[i] = f2bf(q);
        }
    }
}

// ---------------------------------------------------------------------------
// shared epilogue: write transposed bf16 [hw][C] + per-channel partial stats
// ---------------------------------------------------------------------------
__device__ __forceinline__ void epi_t(
    f32x4 (*acc)[7], ushort* __restrict__ yt_img, float* __restrict__ part,
    int C, int pb, int co0, int colane, int lanehi)
{
#pragma unroll
    for (int fi = 0; fi < 2; ++fi) {
#pragma unroll
        for (int j = 0; j < 7; ++j) {
            int hw = j * 16 + colane;
            int co = co0 + fi * 16 + lanehi * 4;
            ushort4 u;
            u.x = f2bf(acc[fi][j][0]); u.y = f2bf(acc[fi][j][1]);
            u.z = f2bf(acc[fi][j][2]); u.w = f2bf(acc[fi][j][3]);
            *reinterpret_cast<ushort4*>(&yt_img[(size_t)hw * C + co]) = u;
        }
        float s[4] = {0, 0, 0, 0}, q[4] = {0, 0, 0, 0};
#pragma unroll
        for (int j = 0; j < 7; ++j)
#pragma unroll
            for (int r = 0; r < 4; ++r) {
                float v = acc[fi][j][r];
                s[r] += v; q[r] += v * v;
            }
#pragma unroll
        for (int m = 1; m < 16; m <<= 1)
#pragma unroll
            for (int r = 0; r < 4; ++r) {
                s[r] += __shfl_xor(s[r], m, 64);
                q[r] += __shfl_xor(q[r], m, 64);
            }
        if (colane == 0) {
#pragma unroll
            for (int r = 0; r < 4; ++r) {
                int co = co0 + fi * 16 + lanehi * 4 + r;
                part[(size_t)co * 448 + pb]       = s[r];
                part[(size_t)(C + co) * 448 + pb] = q[r];
            }
        }
    }
}

// ---------------------------------------------------------------------------
// conv1: 1x1 K=512, fp32 x[n][ci][hw] -> RAW y1t[n][hw][128] bf16 + stats
// ---------------------------------------------------------------------------
__global__ __launch_bounds__(256, 2) void conv1_mfma(
    const float* __restrict__ X, const ushort* __restrict__ Wq,
    ushort* __restrict__ y1t, float* __restrict__ part)
{
    __shared__ ushort lds[2][112 * 40];
    const int n = blockIdx.z, hwt = blockIdx.x;
    const int tid = threadIdx.x, lane = tid & 63, wv = tid >> 6;
    const int colane = lane & 15, lanehi = lane >> 4, klane = lanehi * 8;
    const float* __restrict__ Xn = X + (size_t)n * 512 * HW + hwt * 112;

    int s_hw[4], s_cg[4];
#pragma unroll
    for (int it = 0; it < 4; ++it) {
        int idx = tid + it * 256;
        s_hw[it] = idx % 112; s_cg[it] = idx / 112;
    }
    float4 rv[4];

    auto sload = [&](int kt) {
#pragma unroll
        for (int it = 0; it < 4; ++it) {
            if (it == 3 && tid >= 128) continue;
            const float* xp = Xn + (size_t)(kt * 32 + s_cg[it] * 4) * HW + s_hw[it];
            rv[it].x = xp[0];
            rv[it].y = xp[HW];
            rv[it].z = xp[2 * HW];
            rv[it].w = xp[3 * HW];
        }
    };
    auto swrite = [&](int b) {
#pragma unroll
        for (int it = 0; it < 4; ++it) {
            if (it == 3 && tid >= 128) continue;
            ushort4 u;
            u.x = f2bf(rv[it].x); u.y = f2bf(rv[it].y);
            u.z = f2bf(rv[it].z); u.w = f2bf(rv[it].w);
            *reinterpret_cast<ushort4*>(&lds[b][s_hw[it] * 40 + s_cg[it] * 4]) = u;
        }
    };

    f32x4 acc[2][7];
#pragma unroll
    for (int i = 0; i < 2; ++i)
#pragma unroll
        for (int j = 0; j < 7; ++j) acc[i][j] = (f32x4)(0.f);

    const ushort* A0 = Wq + (size_t)(wv * 32 + colane) * 512 + klane;

    sload(0); swrite(0); __syncthreads();
    for (int kt = 0; kt < 16; ++kt) {
        if (kt < 15) sload(kt + 1);
        const int b = kt & 1;
        bf16x8 a0 = *reinterpret_cast<const bf16x8*>(A0 + kt * 32);
        bf16x8 a1 = *reinterpret_cast<const bf16x8*>(A0 + 16 * 512 + kt * 32);
#pragma unroll
        for (int j = 0; j < 7; ++j) {
            bf16x8 bb = *reinterpret_cast<const bf16x8*>(
                &lds[b][(j * 16 + colane) * 40 + klane]);
            acc[0][j] = __builtin_amdgcn_mfma_f32_16x16x32_bf16(a0, bb, acc[0][j], 0, 0, 0);
            acc[1][j] = __builtin_amdgcn_mfma_f32_16x16x32_bf16(a1, bb, acc[1][j], 0, 0, 0);
        }
        if (kt < 15) swrite(b ^ 1);
        __syncthreads();
    }
    epi_t(acc, y1t + (size_t)n * HW * 128 + (size_t)hwt * 112 * 128, part,
          128, n * 7 + hwt, wv * 32, colane, lanehi);
}

// ---------------------------------------------------------------------------
// conv2: 3x3 pad1. Reads RAW y1t, applies BN1+ReLU during halo staging.
// OOB padding stays zero (reference pads AFTER relu(bn)).
// ---------------------------------------------------------------------------
__global__ __launch_bounds__(256, 2) void conv2_mfma(
    const ushort* __restrict__ y1t, const ushort* __restrict__ Wq,
    ushort* __restrict__ y2t, float* __restrict__ part,
    const float* __restrict__ rs1, const float* __restrict__ sh1)
{
    __shared__ ushort lds[2][2 * 6 * 30 * 40];
    const int n = blockIdx.z, hwt = blockIdx.x;
    const int tid = threadIdx.x, lane = tid & 63, wv = tid >> 6;
    const int colane = lane & 15, lanehi = lane >> 4, klane = lanehi * 8;
    const size_t noff = (size_t)n * HW * 128;
    const int h0 = hwt * 4;

    auto stage = [&](int p, int b) {
        for (int s = tid; s < 1440; s += 256) {
            int rr = s / 240, rem = s - rr * 240, ww = rem >> 3, sl = rem & 7;
            int cc = sl >> 2, g = sl & 3;
            int h = h0 - 1 + rr, w = ww - 1;
            int c0 = (2 * p + cc) * 32 + g * 8;
            uint4 v = make_uint4(0, 0, 0, 0);
            if ((unsigned)h < IW && (unsigned)w < IW) {
                v = *reinterpret_cast<const uint4*>(
                    &y1t[noff + (size_t)(h * IW + w) * 128 + c0]);
                v = bn_pack(v, rs1, sh1, c0);
            }
            *reinterpret_cast<uint4*>(&lds[b][((cc * 6 + rr) * 30 + ww) * 40 + g * 8]) = v;
        }
    };

    int base[7];
#pragma unroll
    for (int j = 0; j < 7; ++j) {
        int hwl = j * 16 + colane;
        int hl = hwl / 28, wl = hwl - hl * 28;
        base[j] = ((hl + 1) * 30 + (wl + 1)) * 40 + klane;
    }

    f32x4 acc[2][7];
#pragma unroll
    for (int i = 0; i < 2; ++i)
#pragma unroll
        for (int j = 0; j < 7; ++j) acc[i][j] = (f32x4)(0.f);

    const ushort* A0 = Wq + (size_t)(wv * 32 + colane) * 1152 + klane;

    auto compute = [&](int p, int b) {
        for (int r = 0; r < 9; ++r) {
            const int dh = r / 3 - 1, dw = r - (r / 3) * 3 - 1;
            const int delta = (dh * 30 + dw) * 40;
#pragma unroll
            for (int cc = 0; cc < 2; ++cc) {
                bf16x8 a0 = *reinterpret_cast<const bf16x8*>(
                    A0 + r * 128 + (2 * p + cc) * 32);
                bf16x8 a1 = *reinterpret_cast<const bf16x8*>(
                    A0 + 16 * 1152 + r * 128 + (2 * p + cc) * 32);
                const ushort* L = &lds[b][cc * 7200];
#pragma unroll
                for (int j = 0; j < 7; ++j) {
                    bf16x8 bb = *reinterpret_cast<const bf16x8*>(&L[base[j] + delta]);
                    acc[0][j] = __builtin_amdgcn_mfma_f32_16x16x32_bf16(a0, bb, acc[0][j], 0, 0, 0);
                    acc[1][j] = __builtin_amdgcn_mfma_f32_16x16x32_bf16(a1, bb, acc[1][j], 0, 0, 0);
                }
            }
        }
    };

    stage(0, 0);
    __syncthreads();

    uint4 pv[6];
#pragma unroll
    for (int it = 0; it < 6; ++it) {
        int s = tid + it * 256;
        if (it == 5 && tid >= 160) continue;
        int rr = s / 240, rem = s - rr * 240, ww = rem >> 3, sl = rem & 7;
        int cc = sl >> 2, g = sl & 3;
        int h = h0 - 1 + rr, w = ww - 1;
        int c0 = (2 + cc) * 32 + g * 8;
        uint4 v = make_uint4(0, 0, 0, 0);
        if ((unsigned)h < IW && (unsigned)w < IW) {
            v = *reinterpret_cast<const uint4*>(
                &y1t[noff + (size_t)(h * IW + w) * 128 + c0]);
            v = bn_pack(v, rs1, sh1, c0);
        }
        pv[it] = v;
    }

    compute(0, 0);

#pragma unroll
    for (int it = 0; it < 6; ++it) {
        int s = tid + it * 256;
        if (it == 5 && tid >= 160) continue;
        int rr = s / 240, rem = s - rr * 240, ww = rem >> 3, sl = rem & 7;
        int cc = sl >> 2, g = sl & 3;
        *reinterpret_cast<uint4*>(&lds[1][((cc * 6 + rr) * 30 + ww) * 40 + g * 8]) = pv[it];
    }
    __syncthreads();
    compute(1, 1);

    epi_t(acc, y2t + noff + (size_t)hwt * 112 * 128, part,
          128, n * 7 + hwt, wv * 32, colane, lanehi);
}

// ---------------------------------------------------------------------------
// conv3: 1x1 K=128. Stages BN2+ReLU(y2t) tile into LDS once, then loops all
// 4 co-tiles (B reused 4x from LDS). Writes RAW y3 + stats.
// ---------------------------------------------------------------------------
template <int BF16OUT>
__global__ __launch_bounds__(256, 2) void conv3_mfma(
    const ushort* __restrict__ y2t, const ushort* __restrict__ Wq,
    void* __restrict__ yout, float* __restrict__ part,
    const float* __restrict__ rs2, const float* __restrict__ sh2)
{
    __shared__ ushort B_lds[112 * 136];
    const int n = blockIdx.z, hwt = blockIdx.x;
    const int tid = threadIdx.x, lane = tid & 63, wv = tid >> 6;
    const int colane = lane & 15, lanehi = lane >> 4, klane = lanehi * 8;
    const size_t noff = (size_t)n * HW * 128;

    // stage 112hw x 128ci with BN2+ReLU: 1792 uint4 slots
    for (int s = tid; s < 1792; s += 256) {
        int hw = s >> 4, g = s & 15, c0 = g * 8;
        uint4 v = *reinterpret_cast<const uint4*>(
            &y2t[noff + (size_t)(hwt * 112 + hw) * 128 + c0]);
        v = bn_pack(v, rs2, sh2, c0);
        *reinterpret_cast<uint4*>(&B_lds[hw * 136 + c0]) = v;
    }
    __syncthreads();

#pragma unroll 1
    for (int cot = 0; cot < 4; ++cot) {
        const int co0 = cot * 128 + wv * 32;
        f32x4 acc[2][7];
#pragma unroll
        for (int i = 0; i < 2; ++i)
#pragma unroll
            for (int j = 0; j < 7; ++j) acc[i][j] = (f32x4)(0.f);

        const ushort* A0 = Wq + (size_t)(co0 + colane) * 128 + klane;
#pragma unroll
        for (int kt = 0; kt < 4; ++kt) {
            bf16x8 a0 = *reinterpret_cast<const bf16x8*>(A0 + kt * 32);
            bf16x8 a1 = *reinterpret_cast<const bf16x8*>(A0 + 16 * 128 + kt * 32);
#pragma unroll
            for (int j = 0; j < 7; ++j) {
                bf16x8 bb = *reinterpret_cast<const bf16x8*>(
                    &B_lds[(j * 16 + colane) * 136 + kt * 32 + klane]);
                acc[0][j] = __builtin_amdgcn_mfma_f32_16x16x32_bf16(a0, bb, acc[0][j], 0, 0, 0);
                acc[1][j] = __builtin_amdgcn_mfma_f32_16x16x32_bf16(a1, bb, acc[1][j], 0, 0, 0);
            }
        }

#pragma unroll
        for (int fi = 0; fi < 2; ++fi) {
#pragma unroll
            for (int j = 0; j < 7; ++j) {
                int cob = co0 + fi * 16 + lanehi * 4;
                int hw = hwt * 112 + j * 16 + colane;
#pragma unroll
                for (int r = 0; r < 4; ++r) {
                    float v = acc[fi][j][r];
                    if (BF16OUT)
                        ((ushort*)yout)[((size_t)n * 512 + cob + r) * HW + hw] = f2bf(v);
                    else
                        ((float*)yout)[((size_t)n * 512 + cob + r) * HW + hw] = v;
                }
            }
            float s[4] = {0, 0, 0, 0}, q[4] = {0, 0, 0, 0};
#pragma unroll
            for (int j = 0; j < 7; ++j)
#pragma unroll
                for (int r = 0; r < 4; ++r) {
                    float v = acc[fi][j][r];
                    s[r] += v; q[r] += v * v;
                }
#pragma unroll
            for (int m = 1; m < 16; m <<= 1)
#pragma unroll
                for (int r = 0; r < 4; ++r) {
                    s[r] += __shfl_xor(s[r], m, 64);
                    q[r] += __shfl_xor(q[r], m, 64);
                }
            if (colane == 0) {
#pragma unroll
                for (int r = 0; r < 4; ++r) {
                    int co = co0 + fi * 16 + lanehi * 4 + r;
                    part[(size_t)co * 448 + (n * 7 + hwt)]         = s[r];
                    part[(size_t)(512 + co) * 448 + (n * 7 + hwt)] = q[r];
                }
            }
        }
    }
}

// ---------------------------------------------------------------------------
// finalize: partials[2C][448] -> rs[c], sh[c]
// ---------------------------------------------------------------------------
__global__ void finalize_stats(const float* __restrict__ part, int C,
    const float* __restrict__ gamma, const float* __restrict__ beta,
    float* __restrict__ rs, float* __restrict__ sh)
{
    int c = blockIdx.x, lane = threadIdx.x;
    double s = 0.0, s2 = 0.0;
    for (int i = lane; i < 448; i += 64) {
        s  += part[(size_t)c * 448 + i];
        s2 += part[(size_t)(C + c) * 448 + i];
    }
#pragma unroll
    for (int m = 1; m < 64; m <<= 1) {
        s  += __shfl_xor(s, m, 64);
        s2 += __shfl_xor(s2, m, 64);
    }
    if (lane == 0) {
        double tot = (double)NB * HW;
        double mean = s / tot;
        float var = (float)(s2 / tot - mean * mean);
        float r = rsqrtf(var + BN_EPS) * gamma[c];
        rs[c] = r;
        sh[c] = beta[c] - (float)mean * r;
    }
}

// ---------------------------------------------------------------------------
// final: out = relu(BN3(y3) + x)
// ---------------------------------------------------------------------------
__global__ void final_f32(float* __restrict__ out, const float* __restrict__ x,
    const float* __restrict__ rs, const float* __restrict__ sh)
{
    int i = blockIdx.x * blockDim.x + threadIdx.x;
    if (i >= NB * 512 * (HW / 4)) return;
    int c = (i / (HW / 4)) & 511;
    float r = rs[c], s = sh[c];
    float4 v = reinterpret_cast<float4*>(out)[i];
    float4 xv = reinterpret_cast<const float4*>(x)[i];
    v.x = fmaxf(fmaf(v.x, r, s) + xv.x, 0.f);
    v.y = fmaxf(fmaf(v.y, r, s) + xv.y, 0.f);
    v.z = fmaxf(fmaf(v.z, r, s) + xv.z, 0.f);
    v.w = fmaxf(fmaf(v.w, r, s) + xv.w, 0.f);
    reinterpret_cast<float4*>(out)[i] = v;
}

__global__ void final_b16(float* __restrict__ out, const float* __restrict__ x,
    const ushort* __restrict__ y3,
    const float* __restrict__ rs, const float* __restrict__ sh)
{
    int i = blockIdx.x * blockDim.x + threadIdx.x;
    if (i >= NB * 512 * 98) return;
    int c = (i / 98) & 511;
    float r = rs[c], s = sh[c];
    uint4 yv = reinterpret_cast<const uint4*>(y3)[i];
    const ushort* u = (const ushort*)&yv;
    float4 x0 = reinterpret_cast<const float4*>(x)[2 * i];
    float4 x1 = reinterpret_cast<const float4*>(x)[2 * i + 1];
    float4 o0, o1;
    o0.x = fmaxf(fmaf(bf2f(u[0]), r, s) + x0.x, 0.f);
    o0.y = fmaxf(fmaf(bf2f(u[1]), r, s) + x0.y, 0.f);
    o0.z = fmaxf(fmaf(bf2f(u[2]), r, s) + x0.z, 0.f);
    o0.w = fmaxf(fmaf(bf2f(u[3]), r, s) + x0.w, 0.f);
    o1.x = fmaxf(fmaf(bf2f(u[4]), r, s) + x1.x, 0.f);
    o1.y = fmaxf(fmaf(bf2f(u[5]), r, s) + x1.y, 0.f);
    o1.z = fmaxf(fmaf(bf2f(u[6]), r, s) + x1.z, 0.f);
    o1.w = fmaxf(fmaf(bf2f(u[7]), r, s) + x1.w, 0.f);
    reinterpret_cast<float4*>(out)[2 * i] = o0;
    reinterpret_cast<float4*>(out)[2 * i + 1] = o1;
}

// ---------------------------------------------------------------------------
extern "C" void kernel_launch(void* const* d_in, const int* in_sizes, int n_in,
                              void* d_out, int out_size, void* d_ws, size_t ws_size,
                              hipStream_t stream)
{
    const float* x   = (const float*)d_in[0];
    const float* w1  = (const float*)d_in[1];
    const float* g1  = (const float*)d_in[3];
    const float* be1 = (const float*)d_in[4];
    const float* w2  = (const float*)d_in[5];
    const float* g2  = (const float*)d_in[7];
    const float* be2 = (const float*)d_in[8];
    const float* w3  = (const float*)d_in[9];
    const float* g3  = (const float*)d_in[11];
    const float* be3 = (const float*)d_in[12];
    float* out = (float*)d_out;

    char* wsb = (char*)d_ws;
    unsigned int* amax = (unsigned int*)wsb;
    float* rs1 = (float*)(wsb + 1024);
    float* sh1 = (float*)(wsb + 1536);
    float* rs2 = (float*)(wsb + 2048);
    float* sh2 = (float*)(wsb + 2560);
    float* rs3 = (float*)(wsb + 3072);
    float* sh3 = (float*)(wsb + 5120);
    float* part1 = (float*)(wsb + 8192);      // [256][448]
    float* part2 = (float*)(wsb + 466944);    // [256][448]
    float* part3 = (float*)(wsb + 925696);    // [1024][448]
    ushort* Wq1 = (ushort*)(wsb + 2760704);
    ushort* Wq2 = (ushort*)(wsb + 2891776);
    ushort* Wq3 = (ushort*)(wsb + 3186688);
    ushort* y1t = (ushort*)(wsb + 3317760);
    ushort* y2t = (ushort*)(wsb + 16162816);
    ushort* y3b = (ushort*)(wsb + 29007872);

    const bool big = ws_size >= (size_t)82000000;

    hipMemsetAsync(amax, 0, 64, stream);
    absmax3_kernel<<<dim3(32, 3), 256, 0, stream>>>(w1, w2, w3, amax);
    prequant3_kernel<<<dim3(96, 3), 256, 0, stream>>>(w1, w2, w3, amax,
                                                      Wq1, Wq2, Wq3);

    conv1_mfma<<<dim3(7, 1, NB), 256, 0, stream>>>(x, Wq1, y1t, part1);
    finalize_stats<<<128, 64, 0, stream>>>(part1, 128, g1, be1, rs1, sh1);

    conv2_mfma<<<dim3(7, 1, NB), 256, 0, stream>>>(y1t, Wq2, y2t, part2,
                                                   rs1, sh1);
    finalize_stats<<<128, 64, 0, stream>>>(part2, 128, g2, be2, rs2, sh2);

    if (big) {
        conv3_mfma<1><<<dim3(7, 1, NB), 256, 0, stream>>>(y2t, Wq3, y3b,
                                                          part3, rs2, sh2);
        finalize_stats<<<512, 64, 0, stream>>>(part3, 512, g3, be3, rs3, sh3);
        final_b16<<<12544, 256, 0, stream>>>(out, x, y3b, rs3, sh3);
    } else {
        conv3_mfma<0><<<dim3(7, 1, NB), 256, 0, stream>>>(y2t, Wq3, out,
                                                          part3, rs2, sh2);
        finalize_stats<<<512, 64, 0, stream>>>(part3, 512, g3, be3, rs3, sh3);
        final_f32<<<25088, 256, 0, stream>>>(out, x, rs3, sh3);
    }
}